// Round 4
// baseline (12201.159 us; speedup 1.0000x reference)
//
#include <hip/hip_runtime.h>
#include <math.h>

// Sinkhorn OT layer, B=8192, C=256, L=100, LAMBD=1.
//
// U = log_u - ||x_i||^2, V = log_v - ||y_j||^2, G[i][j] = 2*dot(x_i,y_j):
//   U[i] = -LSE_j(G[i][j] + V[j]),  V[j] = -LSE_i(G[i][j] + U[i])
// init V[j] = -||y_j||^2. Final: out[i] = y[argmax_j(G[i][j]+V[j])].
//
// d_ws: G only (8192*8192*4 = 256 MiB exactly; ws_size is ~256 MiB — round-2
// abort was scratch tails overflowing d_ws). All small state lives in
// __device__ globals (zero-init at module load; counters self-reset).
//
// L3-residency experiment: G == Infinity Cache size (256 MiB) -> cyclic scans
// thrash. Rows [R_ROWS, B) are accessed with non-temporal loads/stores so the
// first 160 MiB can stay L3-resident across all 200 scans. Correctness-neutral.

#define B 8192
#define C 256
#define LITERS 100
#define CHUNKS 32
#define RPC 256                    // rows per column-pass chunk
#define R_ROWS 5120                // L3-resident rows [0, R_ROWS) = 160 MiB
#define NT_CHUNK (R_ROWS / RPC)    // chunks >= this use NT loads

typedef float f32x4 __attribute__((ext_vector_type(4)));

__device__ __align__(16) float g_U[B];
__device__ __align__(16) float g_V[B];
__device__ __align__(16) float g_pm[CHUNKS * B];
__device__ __align__(16) float g_ps[CHUNKS * B];
__device__ int g_ctr[B / 256];     // 32 jblock counters; self-resetting

// ---------------- init: V[j] = -||y_j||^2 ----------------
__global__ __launch_bounds__(256) void init_V(const float* __restrict__ y) {
    int wave = threadIdx.x >> 6;
    int lane = threadIdx.x & 63;
    int row = blockIdx.x * 4 + wave;
    const f32x4* yr = (const f32x4*)(y + (size_t)row * C);
    f32x4 v = yr[lane];
    float s = v.x * v.x + v.y * v.y + v.z * v.z + v.w * v.w;
    #pragma unroll
    for (int off = 32; off; off >>= 1) s += __shfl_down(s, off, 64);
    if (lane == 0) g_V[row] = -s;
}

// ---------------- GEMM: G = 2 * x @ y^T (f32, 64x64 tiles) ----------------
#define GT 64
#define GKT 64
#define GPAD 4

__global__ __launch_bounds__(256) void gemm_G(const float* __restrict__ x,
                                              const float* __restrict__ y,
                                              float* __restrict__ G) {
    __shared__ float As[GKT][GT + GPAD];   // [k][i]
    __shared__ float Bs[GKT][GT + GPAD];   // [k][j]
    int bi = blockIdx.y * GT;
    int bj = blockIdx.x * GT;
    int t = threadIdx.x;
    int tx = t & 15, ty = t >> 4;
    float acc[4][4] = {};
    for (int kk = 0; kk < C; kk += GKT) {
        #pragma unroll
        for (int l = 0; l < 4; ++l) {
            int e = (t + l * 256) * 4;
            int r = e >> 6;
            int c = e & 63;
            f32x4 va = *(const f32x4*)(x + (size_t)(bi + r) * C + kk + c);
            As[c + 0][r] = va.x; As[c + 1][r] = va.y;
            As[c + 2][r] = va.z; As[c + 3][r] = va.w;
            f32x4 vb = *(const f32x4*)(y + (size_t)(bj + r) * C + kk + c);
            Bs[c + 0][r] = vb.x; Bs[c + 1][r] = vb.y;
            Bs[c + 2][r] = vb.z; Bs[c + 3][r] = vb.w;
        }
        __syncthreads();
        #pragma unroll 8
        for (int k = 0; k < GKT; ++k) {
            f32x4 a = *(const f32x4*)&As[k][ty * 4];
            f32x4 b = *(const f32x4*)&Bs[k][tx * 4];
            float av[4] = {a.x, a.y, a.z, a.w};
            float bv[4] = {b.x, b.y, b.z, b.w};
            #pragma unroll
            for (int ii = 0; ii < 4; ++ii)
                #pragma unroll
                for (int jj = 0; jj < 4; ++jj)
                    acc[ii][jj] = fmaf(av[ii], bv[jj], acc[ii][jj]);
        }
        __syncthreads();
    }
    #pragma unroll
    for (int ii = 0; ii < 4; ++ii) {
        int gi = bi + ty * 4 + ii;
        f32x4 o;
        o.x = 2.0f * acc[ii][0]; o.y = 2.0f * acc[ii][1];
        o.z = 2.0f * acc[ii][2]; o.w = 2.0f * acc[ii][3];
        f32x4* dst = (f32x4*)(G + (size_t)gi * B + bj + tx * 4);
        if (gi >= R_ROWS) __builtin_nontemporal_store(o, dst);
        else              *dst = o;
    }
}

// ---------------- row pass: U[i] = -LSE_j(G[i][j] + V[j]) ----------------
template <bool NT>
__device__ __forceinline__ void row_scan(const float* __restrict__ G, int i, int t,
                                         float& m, float& s) {
    const f32x4* g = (const f32x4*)(G + (size_t)i * B);
    const f32x4* v4 = (const f32x4*)g_V;
    #pragma unroll
    for (int it = 0; it < B / 1024; ++it) {   // 8 iterations
        int idx = it * 256 + t;
        f32x4 gv = NT ? __builtin_nontemporal_load(&g[idx]) : g[idx];
        f32x4 vv = v4[idx];
        float vals[4] = {gv.x + vv.x, gv.y + vv.y, gv.z + vv.z, gv.w + vv.w};
        #pragma unroll
        for (int k = 0; k < 4; ++k) {
            float val = vals[k];
            float m2 = fmaxf(m, val);
            s = s * __expf(m - m2) + __expf(val - m2);
            m = m2;
        }
    }
}

__global__ __launch_bounds__(256) void row_lse(const float* __restrict__ G) {
    int i = blockIdx.x;
    int t = threadIdx.x;
    float m = -INFINITY, s = 0.0f;
    if (i < R_ROWS) row_scan<false>(G, i, t, m, s);
    else            row_scan<true>(G, i, t, m, s);
    __shared__ float sm[256], ss[256];
    sm[t] = m; ss[t] = s;
    __syncthreads();
    #pragma unroll
    for (int off = 128; off; off >>= 1) {
        if (t < off) {
            float mo = sm[t + off], so = ss[t + off];
            float m1 = sm[t],       s1 = ss[t];
            float m2 = fmaxf(m1, mo);
            ss[t] = s1 * __expf(m1 - m2) + so * __expf(mo - m2);
            sm[t] = m2;
        }
        __syncthreads();
    }
    if (t == 0) g_U[i] = -(sm[0] + logf(ss[0]));
}

// ------- column pass, fused combine (split-K last-block pattern) -------
__global__ __launch_bounds__(256) void col_pass(const float* __restrict__ G) {
    int t = threadIdx.x;
    int jb = blockIdx.x;          // 0..31
    int chunk = blockIdx.y;       // 0..31
    int j = jb * 256 + t;
    int i0 = chunk * RPC;
    __shared__ float Us[RPC];
    Us[t] = g_U[i0 + t];
    __syncthreads();
    float m = -INFINITY, s = 0.0f;
    const float* gp = G + (size_t)i0 * B + j;
    if (chunk < NT_CHUNK) {
        #pragma unroll 8
        for (int r = 0; r < RPC; ++r) {
            float val = gp[(size_t)r * B] + Us[r];
            float m2 = fmaxf(m, val);
            s = s * __expf(m - m2) + __expf(val - m2);
            m = m2;
        }
    } else {
        #pragma unroll 8
        for (int r = 0; r < RPC; ++r) {
            float val = __builtin_nontemporal_load(gp + (size_t)r * B) + Us[r];
            float m2 = fmaxf(m, val);
            s = s * __expf(m - m2) + __expf(val - m2);
            m = m2;
        }
    }
    // publish partials at agent scope (cross-XCD visible, no L2 staleness)
    __hip_atomic_store(&g_pm[chunk * B + j], m, __ATOMIC_RELAXED, __HIP_MEMORY_SCOPE_AGENT);
    __hip_atomic_store(&g_ps[chunk * B + j], s, __ATOMIC_RELAXED, __HIP_MEMORY_SCOPE_AGENT);
    __syncthreads();
    __shared__ int lastFlag;
    if (t == 0) {
        int old = __hip_atomic_fetch_add(&g_ctr[jb], 1, __ATOMIC_ACQ_REL,
                                         __HIP_MEMORY_SCOPE_AGENT);
        lastFlag = (old == CHUNKS - 1);
    }
    __syncthreads();
    if (lastFlag) {   // last-arriving block for this jblock combines 32 partials
        float mm = -INFINITY, ssum = 0.0f;
        #pragma unroll
        for (int c = 0; c < CHUNKS; ++c) {
            float mc = __hip_atomic_load(&g_pm[c * B + j], __ATOMIC_RELAXED,
                                         __HIP_MEMORY_SCOPE_AGENT);
            float sc = __hip_atomic_load(&g_ps[c * B + j], __ATOMIC_RELAXED,
                                         __HIP_MEMORY_SCOPE_AGENT);
            float m2 = fmaxf(mm, mc);
            ssum = ssum * __expf(mm - m2) + sc * __expf(mc - m2);
            mm = m2;
        }
        g_V[j] = -(mm + logf(ssum));   // read by next dispatch (stream-ordered)
        if (t == 0)
            __hip_atomic_store(&g_ctr[jb], 0, __ATOMIC_RELAXED, __HIP_MEMORY_SCOPE_AGENT);
    }
}

// ---------------- argmax + gather: out[i] = y[argmax_j(G[i][j]+V[j])] ----------------
__global__ __launch_bounds__(256) void argmax_out(const float* __restrict__ G,
                                                  const float* __restrict__ y,
                                                  float* __restrict__ out) {
    int i = blockIdx.x;
    int t = threadIdx.x;
    const f32x4* g = (const f32x4*)(G + (size_t)i * B);
    const f32x4* v4 = (const f32x4*)g_V;
    bool nt = (i >= R_ROWS);
    float best = -INFINITY;
    int bj = B;
    #pragma unroll
    for (int it = 0; it < B / 1024; ++it) {
        int idx = it * 256 + t;
        f32x4 gv = nt ? __builtin_nontemporal_load(&g[idx]) : g[idx];
        f32x4 vv = v4[idx];
        float vals[4] = {gv.x + vv.x, gv.y + vv.y, gv.z + vv.z, gv.w + vv.w};
        #pragma unroll
        for (int k = 0; k < 4; ++k) {
            int j = idx * 4 + k;
            if (vals[k] > best) { best = vals[k]; bj = j; }
        }
    }
    __shared__ float bm[256];
    __shared__ int   bidx[256];
    bm[t] = best; bidx[t] = bj;
    __syncthreads();
    #pragma unroll
    for (int off = 128; off; off >>= 1) {
        if (t < off) {
            float om = bm[t + off]; int oj = bidx[t + off];
            if (om > bm[t] || (om == bm[t] && oj < bidx[t])) { bm[t] = om; bidx[t] = oj; }
        }
        __syncthreads();
    }
    int jstar = bidx[0];
    out[(size_t)i * C + t] = y[(size_t)jstar * C + t];
}

extern "C" void kernel_launch(void* const* d_in, const int* in_sizes, int n_in,
                              void* d_out, int out_size, void* d_ws, size_t ws_size,
                              hipStream_t stream) {
    const float* x = (const float*)d_in[0];
    const float* y = (const float*)d_in[1];
    float* out = (float*)d_out;
    float* G = (float*)d_ws;     // exactly 256 MiB

    init_V<<<B / 4, 256, 0, stream>>>(y);
    gemm_G<<<dim3(B / GT, B / GT), 256, 0, stream>>>(x, y, G);
    for (int l = 0; l < LITERS; ++l) {
        row_lse<<<B, 256, 0, stream>>>(G);
        col_pass<<<dim3(B / 256, CHUNKS), 256, 0, stream>>>(G);
    }
    argmax_out<<<B, 256, 0, stream>>>(G, y, out);
}

// Round 5
// 11970.163 us; speedup vs baseline: 1.0193x; 1.0193x over previous
//
#include <hip/hip_runtime.h>
#include <math.h>

// Sinkhorn OT layer, B=8192, C=256, L=100, LAMBD=1.
//
// U = log_u - ||x_i||^2, V = log_v - ||y_j||^2, G[i][j] = 2*dot(x_i,y_j):
//   U[i] = -LSE_j(G[i][j] + V[j]),  V[j] = -LSE_i(G[i][j] + U[i])
// init V[j] = -||y_j||^2. Final: out[i] = y[argmax_j(G[i][j]+V[j])].
//
// d_ws: G only (8192*8192*4 = 256 MiB exactly). Small state in __device__
// globals (zero-init at load; counters self-reset each dispatch).
//
// R4 post-mortem: non-temporal hints REGRESSED iteration kernels ~37%
// (NT loads forfeit L2/L3 service on gfx950) -> fully reverted.
// GEMM had 1.17e8 LDS bank conflicts from transpose staging writes ->
// natural [row][k] tile layout, float4 staging, interleaved B columns.

#define B 8192
#define C 256
#define LITERS 100
#define CHUNKS 32
#define RPC 256                    // rows per column-pass chunk

typedef float f32x4 __attribute__((ext_vector_type(4)));

__device__ __align__(16) float g_U[B];
__device__ __align__(16) float g_V[B];
__device__ __align__(16) float g_pm[CHUNKS * B];
__device__ __align__(16) float g_ps[CHUNKS * B];
__device__ int g_ctr[B / 256];     // 32 jblock counters; self-resetting

// ---------------- init: V[j] = -||y_j||^2 ----------------
__global__ __launch_bounds__(256) void init_V(const float* __restrict__ y) {
    int wave = threadIdx.x >> 6;
    int lane = threadIdx.x & 63;
    int row = blockIdx.x * 4 + wave;
    const f32x4* yr = (const f32x4*)(y + (size_t)row * C);
    f32x4 v = yr[lane];
    float s = v.x * v.x + v.y * v.y + v.z * v.z + v.w * v.w;
    #pragma unroll
    for (int off = 32; off; off >>= 1) s += __shfl_down(s, off, 64);
    if (lane == 0) g_V[row] = -s;
}

// ---------------- GEMM: G = 2 * x @ y^T (f32, 64x64 tiles) ----------------
// LDS tiles kept in natural [row][k] layout (no transpose on staging).
// Thread (tx,ty) computes A-rows {ty*4+ii} x B-rows {tx+16*jj}.
// b-frag reads: 16 tx -> banks 4*tx mod 32 -> 2-way (free, m136).
#define GT 64
#define GKT 64
#define LSTR (GKT + 4)   // 68 floats; float4-aligned offsets

__global__ __launch_bounds__(256) void gemm_G(const float* __restrict__ x,
                                              const float* __restrict__ y,
                                              float* __restrict__ G) {
    __shared__ float As[GT][LSTR];   // [i][k]
    __shared__ float Bs[GT][LSTR];   // [j][k]
    int bi = blockIdx.y * GT;
    int bj = blockIdx.x * GT;
    int t = threadIdx.x;
    int tx = t & 15, ty = t >> 4;
    float acc[4][4] = {};
    for (int kk = 0; kk < C; kk += GKT) {
        // stage 64x64 of x and y: 1024 float4 each, 4 per thread, no transpose
        #pragma unroll
        for (int l = 0; l < 4; ++l) {
            int idx = t + l * 256;         // float4 index in tile
            int r = idx >> 4;              // tile row 0..63
            int c4 = idx & 15;             // float4 col 0..15
            *(f32x4*)&As[r][c4 * 4] =
                *(const f32x4*)(x + (size_t)(bi + r) * C + kk + c4 * 4);
            *(f32x4*)&Bs[r][c4 * 4] =
                *(const f32x4*)(y + (size_t)(bj + r) * C + kk + c4 * 4);
        }
        __syncthreads();
        #pragma unroll
        for (int k4 = 0; k4 < GKT / 4; ++k4) {
            f32x4 a[4], b[4];
            #pragma unroll
            for (int ii = 0; ii < 4; ++ii)
                a[ii] = *(const f32x4*)&As[ty * 4 + ii][k4 * 4];
            #pragma unroll
            for (int jj = 0; jj < 4; ++jj)
                b[jj] = *(const f32x4*)&Bs[tx + 16 * jj][k4 * 4];
            #pragma unroll
            for (int ii = 0; ii < 4; ++ii)
                #pragma unroll
                for (int jj = 0; jj < 4; ++jj) {
                    acc[ii][jj] = fmaf(a[ii].x, b[jj].x, acc[ii][jj]);
                    acc[ii][jj] = fmaf(a[ii].y, b[jj].y, acc[ii][jj]);
                    acc[ii][jj] = fmaf(a[ii].z, b[jj].z, acc[ii][jj]);
                    acc[ii][jj] = fmaf(a[ii].w, b[jj].w, acc[ii][jj]);
                }
        }
        __syncthreads();
    }
    #pragma unroll
    for (int ii = 0; ii < 4; ++ii) {
        int gi = bi + ty * 4 + ii;
        #pragma unroll
        for (int jj = 0; jj < 4; ++jj)
            G[(size_t)gi * B + bj + tx + 16 * jj] = 2.0f * acc[ii][jj];
    }
}

// ---------------- row pass: U[i] = -LSE_j(G[i][j] + V[j]) ----------------
__global__ __launch_bounds__(256) void row_lse(const float* __restrict__ G) {
    int i = blockIdx.x;
    int t = threadIdx.x;
    const f32x4* g = (const f32x4*)(G + (size_t)i * B);
    const f32x4* v4 = (const f32x4*)g_V;
    float m = -INFINITY, s = 0.0f;
    #pragma unroll
    for (int it = 0; it < B / 1024; ++it) {   // 8 iterations
        int idx = it * 256 + t;
        f32x4 gv = g[idx];
        f32x4 vv = v4[idx];
        float vals[4] = {gv.x + vv.x, gv.y + vv.y, gv.z + vv.z, gv.w + vv.w};
        #pragma unroll
        for (int k = 0; k < 4; ++k) {
            float val = vals[k];
            float m2 = fmaxf(m, val);
            s = s * __expf(m - m2) + __expf(val - m2);
            m = m2;
        }
    }
    __shared__ float sm[256], ss[256];
    sm[t] = m; ss[t] = s;
    __syncthreads();
    #pragma unroll
    for (int off = 128; off; off >>= 1) {
        if (t < off) {
            float mo = sm[t + off], so = ss[t + off];
            float m1 = sm[t],       s1 = ss[t];
            float m2 = fmaxf(m1, mo);
            ss[t] = s1 * __expf(m1 - m2) + so * __expf(mo - m2);
            sm[t] = m2;
        }
        __syncthreads();
    }
    if (t == 0) g_U[i] = -(sm[0] + logf(ss[0]));
}

// ------- column pass, fused combine (split-K last-block pattern) -------
__global__ __launch_bounds__(256) void col_pass(const float* __restrict__ G) {
    int t = threadIdx.x;
    int jb = blockIdx.x;          // 0..31
    int chunk = blockIdx.y;       // 0..31
    int j = jb * 256 + t;
    int i0 = chunk * RPC;
    __shared__ float Us[RPC];
    Us[t] = g_U[i0 + t];
    __syncthreads();
    float m = -INFINITY, s = 0.0f;
    const float* gp = G + (size_t)i0 * B + j;
    #pragma unroll 8
    for (int r = 0; r < RPC; ++r) {
        float val = gp[(size_t)r * B] + Us[r];
        float m2 = fmaxf(m, val);
        s = s * __expf(m - m2) + __expf(val - m2);
        m = m2;
    }
    // publish partials at agent scope (cross-XCD visible)
    __hip_atomic_store(&g_pm[chunk * B + j], m, __ATOMIC_RELAXED, __HIP_MEMORY_SCOPE_AGENT);
    __hip_atomic_store(&g_ps[chunk * B + j], s, __ATOMIC_RELAXED, __HIP_MEMORY_SCOPE_AGENT);
    __syncthreads();
    __shared__ int lastFlag;
    if (t == 0) {
        int old = __hip_atomic_fetch_add(&g_ctr[jb], 1, __ATOMIC_ACQ_REL,
                                         __HIP_MEMORY_SCOPE_AGENT);
        lastFlag = (old == CHUNKS - 1);
    }
    __syncthreads();
    if (lastFlag) {   // last-arriving block for this jblock combines 32 partials
        float mm = -INFINITY, ssum = 0.0f;
        #pragma unroll
        for (int c = 0; c < CHUNKS; ++c) {
            float mc = __hip_atomic_load(&g_pm[c * B + j], __ATOMIC_RELAXED,
                                         __HIP_MEMORY_SCOPE_AGENT);
            float sc = __hip_atomic_load(&g_ps[c * B + j], __ATOMIC_RELAXED,
                                         __HIP_MEMORY_SCOPE_AGENT);
            float m2 = fmaxf(mm, mc);
            ssum = ssum * __expf(mm - m2) + sc * __expf(mc - m2);
            mm = m2;
        }
        g_V[j] = -(mm + logf(ssum));   // read by next dispatch (stream-ordered)
        if (t == 0)
            __hip_atomic_store(&g_ctr[jb], 0, __ATOMIC_RELAXED, __HIP_MEMORY_SCOPE_AGENT);
    }
}

// ---------------- argmax + gather: out[i] = y[argmax_j(G[i][j]+V[j])] ----------------
__global__ __launch_bounds__(256) void argmax_out(const float* __restrict__ G,
                                                  const float* __restrict__ y,
                                                  float* __restrict__ out) {
    int i = blockIdx.x;
    int t = threadIdx.x;
    const f32x4* g = (const f32x4*)(G + (size_t)i * B);
    const f32x4* v4 = (const f32x4*)g_V;
    float best = -INFINITY;
    int bj = B;
    #pragma unroll
    for (int it = 0; it < B / 1024; ++it) {
        int idx = it * 256 + t;
        f32x4 gv = g[idx];
        f32x4 vv = v4[idx];
        float vals[4] = {gv.x + vv.x, gv.y + vv.y, gv.z + vv.z, gv.w + vv.w};
        #pragma unroll
        for (int k = 0; k < 4; ++k) {
            int j = idx * 4 + k;
            if (vals[k] > best) { best = vals[k]; bj = j; }
        }
    }
    __shared__ float bm[256];
    __shared__ int   bidx[256];
    bm[t] = best; bidx[t] = bj;
    __syncthreads();
    #pragma unroll
    for (int off = 128; off; off >>= 1) {
        if (t < off) {
            float om = bm[t + off]; int oj = bidx[t + off];
            if (om > bm[t] || (om == bm[t] && oj < bidx[t])) { bm[t] = om; bidx[t] = oj; }
        }
        __syncthreads();
    }
    int jstar = bidx[0];
    out[(size_t)i * C + t] = y[(size_t)jstar * C + t];
}

extern "C" void kernel_launch(void* const* d_in, const int* in_sizes, int n_in,
                              void* d_out, int out_size, void* d_ws, size_t ws_size,
                              hipStream_t stream) {
    const float* x = (const float*)d_in[0];
    const float* y = (const float*)d_in[1];
    float* out = (float*)d_out;
    float* G = (float*)d_ws;     // exactly 256 MiB

    init_V<<<B / 4, 256, 0, stream>>>(y);
    gemm_G<<<dim3(B / GT, B / GT), 256, 0, stream>>>(x, y, G);
    for (int l = 0; l < LITERS; ++l) {
        row_lse<<<B, 256, 0, stream>>>(G);
        col_pass<<<dim3(B / 256, CHUNKS), 256, 0, stream>>>(G);
    }
    argmax_out<<<B, 256, 0, stream>>>(G, y, out);
}

// Round 6
// 9164.391 us; speedup vs baseline: 1.3314x; 1.3062x over previous
//
#include <hip/hip_runtime.h>
#include <math.h>

// Sinkhorn OT layer, B=8192, C=256, L=100, LAMBD=1.
//
// U = log_u - ||x_i||^2, V = log_v - ||y_j||^2, G[i][j] = 2*dot(x_i,y_j):
//   U[i] = -LSE_j(G[i][j] + V[j]),  V[j] = -LSE_i(G[i][j] + U[i])
// init V[j] = -||y_j||^2. Final: out[i] = y[argmax_j(G[i][j]+V[j])].
//
// d_ws: G only (8192*8192*4 = 256 MiB exactly). Small state in __device__
// globals, accessed with PLAIN loads/stores only; cross-dispatch visibility
// comes from kernel boundaries (stream-ordered dispatches).
//
// R5 post-mortem: fused split-K combine with agent-scope ACQ_REL atomics
// cost ~25 us/iter (acquire => per-block L2 invalidate x1024, release
// writebacks, MALL-bypass partial traffic) -> reverted to separate
// col_partial + col_combine kernels (R3 structure, known 87 us/iter).
// Kept: conflict-free GEMM (R5: 1.17e8 -> 0 conflicts), device-global
// scratch (no fold_V pass), argmax adds V inline.
// New (free): zigzag traversal -- col pass walks rows DESCENDING, row pass
// ASCENDING, so each pass starts on the MALL-freshest end of G.

#define B 8192
#define C 256
#define LITERS 100
#define CHUNKS 32
#define RPC 256                    // rows per column-pass chunk

typedef float f32x4 __attribute__((ext_vector_type(4)));

__device__ __align__(16) float g_U[B];
__device__ __align__(16) float g_V[B];
__device__ __align__(16) float g_pm[CHUNKS * B];
__device__ __align__(16) float g_ps[CHUNKS * B];

// ---------------- init: V[j] = -||y_j||^2 ----------------
__global__ __launch_bounds__(256) void init_V(const float* __restrict__ y) {
    int wave = threadIdx.x >> 6;
    int lane = threadIdx.x & 63;
    int row = blockIdx.x * 4 + wave;
    const f32x4* yr = (const f32x4*)(y + (size_t)row * C);
    f32x4 v = yr[lane];
    float s = v.x * v.x + v.y * v.y + v.z * v.z + v.w * v.w;
    #pragma unroll
    for (int off = 32; off; off >>= 1) s += __shfl_down(s, off, 64);
    if (lane == 0) g_V[row] = -s;
}

// ---------------- GEMM: G = 2 * x @ y^T (f32, 64x64 tiles) ----------------
// LDS tiles in natural [row][k] layout (no transpose on staging, float4 IO).
// Thread (tx,ty) computes A-rows {ty*4+ii} x B-rows {tx+16*jj}.
#define GT 64
#define GKT 64
#define LSTR (GKT + 4)   // 68 floats; float4-aligned offsets

__global__ __launch_bounds__(256) void gemm_G(const float* __restrict__ x,
                                              const float* __restrict__ y,
                                              float* __restrict__ G) {
    __shared__ float As[GT][LSTR];   // [i][k]
    __shared__ float Bs[GT][LSTR];   // [j][k]
    int bi = blockIdx.y * GT;
    int bj = blockIdx.x * GT;
    int t = threadIdx.x;
    int tx = t & 15, ty = t >> 4;
    float acc[4][4] = {};
    for (int kk = 0; kk < C; kk += GKT) {
        #pragma unroll
        for (int l = 0; l < 4; ++l) {
            int idx = t + l * 256;         // float4 index in tile
            int r = idx >> 4;              // tile row 0..63
            int c4 = idx & 15;             // float4 col 0..15
            *(f32x4*)&As[r][c4 * 4] =
                *(const f32x4*)(x + (size_t)(bi + r) * C + kk + c4 * 4);
            *(f32x4*)&Bs[r][c4 * 4] =
                *(const f32x4*)(y + (size_t)(bj + r) * C + kk + c4 * 4);
        }
        __syncthreads();
        #pragma unroll
        for (int k4 = 0; k4 < GKT / 4; ++k4) {
            f32x4 a[4], b[4];
            #pragma unroll
            for (int ii = 0; ii < 4; ++ii)
                a[ii] = *(const f32x4*)&As[ty * 4 + ii][k4 * 4];
            #pragma unroll
            for (int jj = 0; jj < 4; ++jj)
                b[jj] = *(const f32x4*)&Bs[tx + 16 * jj][k4 * 4];
            #pragma unroll
            for (int ii = 0; ii < 4; ++ii)
                #pragma unroll
                for (int jj = 0; jj < 4; ++jj) {
                    acc[ii][jj] = fmaf(a[ii].x, b[jj].x, acc[ii][jj]);
                    acc[ii][jj] = fmaf(a[ii].y, b[jj].y, acc[ii][jj]);
                    acc[ii][jj] = fmaf(a[ii].z, b[jj].z, acc[ii][jj]);
                    acc[ii][jj] = fmaf(a[ii].w, b[jj].w, acc[ii][jj]);
                }
        }
        __syncthreads();
    }
    #pragma unroll
    for (int ii = 0; ii < 4; ++ii) {
        int gi = bi + ty * 4 + ii;
        #pragma unroll
        for (int jj = 0; jj < 4; ++jj)
            G[(size_t)gi * B + bj + tx + 16 * jj] = 2.0f * acc[ii][jj];
    }
}

// ---------------- row pass: U[i] = -LSE_j(G[i][j] + V[j]) ----------------
__global__ __launch_bounds__(256) void row_lse(const float* __restrict__ G) {
    int i = blockIdx.x;                     // ascending rows
    int t = threadIdx.x;
    const f32x4* g = (const f32x4*)(G + (size_t)i * B);
    const f32x4* v4 = (const f32x4*)g_V;
    float m = -INFINITY, s = 0.0f;
    #pragma unroll
    for (int it = 0; it < B / 1024; ++it) {   // 8 iterations
        int idx = it * 256 + t;
        f32x4 gv = g[idx];
        f32x4 vv = v4[idx];
        float vals[4] = {gv.x + vv.x, gv.y + vv.y, gv.z + vv.z, gv.w + vv.w};
        #pragma unroll
        for (int k = 0; k < 4; ++k) {
            float val = vals[k];
            float m2 = fmaxf(m, val);
            s = s * __expf(m - m2) + __expf(val - m2);
            m = m2;
        }
    }
    __shared__ float sm[256], ss[256];
    sm[t] = m; ss[t] = s;
    __syncthreads();
    #pragma unroll
    for (int off = 128; off; off >>= 1) {
        if (t < off) {
            float mo = sm[t + off], so = ss[t + off];
            float m1 = sm[t],       s1 = ss[t];
            float m2 = fmaxf(m1, mo);
            ss[t] = s1 * __expf(m1 - m2) + so * __expf(mo - m2);
            sm[t] = m2;
        }
        __syncthreads();
    }
    if (t == 0) g_U[i] = -(sm[0] + logf(ss[0]));
}

// ------- column pass (partials): per (chunk, j): online LSE over 256 rows -------
// Zigzag: chunks and within-chunk rows walk DESCENDING so this pass starts
// on the rows row_lse touched last (MALL-freshest).
__global__ __launch_bounds__(256) void col_partial(const float* __restrict__ G) {
    int t = threadIdx.x;
    int j = blockIdx.x * 256 + t;
    int chunk = (CHUNKS - 1) - blockIdx.y;
    int i0 = chunk * RPC;
    __shared__ float Us[RPC];
    Us[t] = g_U[i0 + t];
    __syncthreads();
    float m = -INFINITY, s = 0.0f;
    const float* gp = G + (size_t)i0 * B + j;
    #pragma unroll 8
    for (int r = RPC - 1; r >= 0; --r) {      // descending rows
        float val = gp[(size_t)r * B] + Us[r];
        float m2 = fmaxf(m, val);
        s = s * __expf(m - m2) + __expf(val - m2);
        m = m2;
    }
    g_pm[chunk * B + j] = m;
    g_ps[chunk * B + j] = s;
}

// ---------------- column combine: V[j] = -(LSE of 32 partials) ----------------
__global__ __launch_bounds__(256) void col_combine() {
    int j = blockIdx.x * 256 + threadIdx.x;
    float m = -INFINITY, s = 0.0f;
    #pragma unroll
    for (int c = 0; c < CHUNKS; ++c) {
        float mc = g_pm[c * B + j], sc = g_ps[c * B + j];
        float m2 = fmaxf(m, mc);
        s = s * __expf(m - m2) + sc * __expf(mc - m2);
        m = m2;
    }
    g_V[j] = -(m + logf(s));
}

// ---------------- argmax + gather: out[i] = y[argmax_j(G[i][j]+V[j])] ----------------
__global__ __launch_bounds__(256) void argmax_out(const float* __restrict__ G,
                                                  const float* __restrict__ y,
                                                  float* __restrict__ out) {
    int i = blockIdx.x;                      // ascending (last col pass ended low)
    int t = threadIdx.x;
    const f32x4* g = (const f32x4*)(G + (size_t)i * B);
    const f32x4* v4 = (const f32x4*)g_V;
    float best = -INFINITY;
    int bj = B;
    #pragma unroll
    for (int it = 0; it < B / 1024; ++it) {
        int idx = it * 256 + t;
        f32x4 gv = g[idx];
        f32x4 vv = v4[idx];
        float vals[4] = {gv.x + vv.x, gv.y + vv.y, gv.z + vv.z, gv.w + vv.w};
        #pragma unroll
        for (int k = 0; k < 4; ++k) {
            int j = idx * 4 + k;
            if (vals[k] > best) { best = vals[k]; bj = j; }
        }
    }
    __shared__ float bm[256];
    __shared__ int   bidx[256];
    bm[t] = best; bidx[t] = bj;
    __syncthreads();
    #pragma unroll
    for (int off = 128; off; off >>= 1) {
        if (t < off) {
            float om = bm[t + off]; int oj = bidx[t + off];
            if (om > bm[t] || (om == bm[t] && oj < bidx[t])) { bm[t] = om; bidx[t] = oj; }
        }
        __syncthreads();
    }
    int jstar = bidx[0];
    out[(size_t)i * C + t] = y[(size_t)jstar * C + t];
}

extern "C" void kernel_launch(void* const* d_in, const int* in_sizes, int n_in,
                              void* d_out, int out_size, void* d_ws, size_t ws_size,
                              hipStream_t stream) {
    const float* x = (const float*)d_in[0];
    const float* y = (const float*)d_in[1];
    float* out = (float*)d_out;
    float* G = (float*)d_ws;     // exactly 256 MiB

    init_V<<<B / 4, 256, 0, stream>>>(y);
    gemm_G<<<dim3(B / GT, B / GT), 256, 0, stream>>>(x, y, G);
    for (int l = 0; l < LITERS; ++l) {
        row_lse<<<B, 256, 0, stream>>>(G);
        col_partial<<<dim3(B / 256, CHUNKS), 256, 0, stream>>>(G);
        col_combine<<<B / 256, 256, 0, stream>>>();
    }
    argmax_out<<<B, 256, 0, stream>>>(G, y, out);
}